// Round 1
// baseline (907.041 us; speedup 1.0000x reference)
//
#include <hip/hip_runtime.h>
#include <hip/hip_bf16.h>

#define N_NODES 50000
#define N_EDGES 800000
#define E_TOTAL (N_EDGES + N_NODES) /* 850000, self-loops appended */
#define FDIM 256

// ---------------------------------------------------------------------------
// CSR build: degree count -> exclusive scan -> scatter (by dst)
// ---------------------------------------------------------------------------
__global__ __launch_bounds__(256) void deg_kernel(const int* __restrict__ ei,
                                                  int* __restrict__ deg) {
  int e = blockIdx.x * 256 + threadIdx.x;
  if (e >= E_TOTAL) return;
  int d = (e < N_EDGES) ? ei[N_EDGES + e] : (e - N_EDGES);
  atomicAdd(&deg[d], 1);
}

__global__ __launch_bounds__(1024) void scan_kernel(const int* __restrict__ deg,
                                                    int* __restrict__ row_ptr) {
  __shared__ int sh[1024];
  __shared__ int carry_sh;
  const int t = threadIdx.x;
  if (t == 0) carry_sh = 0;
  __syncthreads();
  const int ITEMS = 8;
  for (int base = 0; base < N_NODES; base += 1024 * ITEMS) {
    int i0 = base + t * ITEMS;
    int v[ITEMS];
    int s = 0;
#pragma unroll
    for (int j = 0; j < ITEMS; j++) {
      v[j] = (i0 + j < N_NODES) ? deg[i0 + j] : 0;
      s += v[j];
    }
    sh[t] = s;
    __syncthreads();
    for (int off = 1; off < 1024; off <<= 1) {
      int tv = (t >= off) ? sh[t - off] : 0;
      __syncthreads();
      sh[t] += tv;
      __syncthreads();
    }
    int excl = sh[t] - s;
    int run = carry_sh + excl;
#pragma unroll
    for (int j = 0; j < ITEMS; j++) {
      if (i0 + j < N_NODES) row_ptr[i0 + j] = run;
      run += v[j];
    }
    int total = sh[1023];
    __syncthreads();
    if (t == 0) carry_sh += total;
    __syncthreads();
  }
  if (t == 0) row_ptr[N_NODES] = carry_sh;
}

__global__ __launch_bounds__(256) void scatter_kernel(const int* __restrict__ ei,
                                                      const int* __restrict__ row_ptr,
                                                      int* __restrict__ cursor,
                                                      int* __restrict__ csr_src) {
  int e = blockIdx.x * 256 + threadIdx.x;
  if (e >= E_TOTAL) return;
  int s, d;
  if (e < N_EDGES) {
    s = ei[e];
    d = ei[N_EDGES + e];
  } else {
    s = d = e - N_EDGES;
  }
  int pos = atomicAdd(&cursor[d], 1);
  csr_src[row_ptr[d] + pos] = s;
}

// ---------------------------------------------------------------------------
// f32 GEMM: C[M,256] = A[M,256] * B[256,256], row-major
// 64x64 tile, 256 threads, 4x4 microtile
// ---------------------------------------------------------------------------
__global__ __launch_bounds__(256) void gemm_f32(const float* __restrict__ A,
                                                const float* __restrict__ B,
                                                float* __restrict__ C, int M) {
  __shared__ float As[16][64];
  __shared__ float Bs[16][64];
  const int t = threadIdx.x;
  const int tx = t & 15, ty = t >> 4;
  const int row0 = blockIdx.x * 64, col0 = blockIdx.y * 64;
  float acc[4][4] = {};
  const int ar = t >> 2, ac = (t & 3) * 4;  // A-tile load coords
  const int br = t >> 4, bc = (t & 15) * 4; // B-tile load coords
  for (int k0 = 0; k0 < 256; k0 += 16) {
    float4 av = make_float4(0.f, 0.f, 0.f, 0.f);
    if (row0 + ar < M) av = *(const float4*)&A[(size_t)(row0 + ar) * 256 + k0 + ac];
    As[ac + 0][ar] = av.x;
    As[ac + 1][ar] = av.y;
    As[ac + 2][ar] = av.z;
    As[ac + 3][ar] = av.w;
    *(float4*)&Bs[br][bc] = *(const float4*)&B[(size_t)(k0 + br) * 256 + col0 + bc];
    __syncthreads();
#pragma unroll
    for (int k = 0; k < 16; k++) {
      float a0[4], b0[4];
      *(float4*)a0 = *(const float4*)&As[k][ty * 4];
      *(float4*)b0 = *(const float4*)&Bs[k][tx * 4];
#pragma unroll
      for (int i = 0; i < 4; i++)
#pragma unroll
        for (int j = 0; j < 4; j++) acc[i][j] = fmaf(a0[i], b0[j], acc[i][j]);
    }
    __syncthreads();
  }
#pragma unroll
  for (int i = 0; i < 4; i++) {
    int r = row0 + ty * 4 + i;
    if (r < M)
      *(float4*)&C[(size_t)r * 256 + col0 + tx * 4] =
          make_float4(acc[i][0], acc[i][1], acc[i][2], acc[i][3]);
  }
}

// ---------------------------------------------------------------------------
// per-node attention coefficients: a_s[n,h] = sum_c XH[n,h,c]*att_s[h,c]
// ---------------------------------------------------------------------------
template <int H>
__global__ __launch_bounds__(256) void att_kernel(const float* __restrict__ XH,
                                                  const float* __restrict__ att_s,
                                                  const float* __restrict__ att_d,
                                                  float* __restrict__ a_s,
                                                  float* __restrict__ a_d) {
  const int n = blockIdx.x;
  const int t = threadIdx.x;
  const int lane = t & 63, w = t >> 6;
  float xv = XH[(size_t)n * 256 + t];
  float vs = xv * att_s[t];
  float vd = xv * att_d[t];
#pragma unroll
  for (int off = 1; off < 64; off <<= 1) {
    vs += __shfl_xor(vs, off, 64);
    vd += __shfl_xor(vd, off, 64);
  }
  if constexpr (H == 4) {
    if (lane == 0) {
      a_s[n * 4 + w] = vs;
      a_d[n * 4 + w] = vd;
    }
  } else {
    __shared__ float ss[4], sd[4];
    if (lane == 0) {
      ss[w] = vs;
      sd[w] = vd;
    }
    __syncthreads();
    if (t == 0) {
      a_s[n] = ss[0] + ss[1] + ss[2] + ss[3];
      a_d[n] = sd[0] + sd[1] + sd[2] + sd[3];
    }
  }
}

// ---------------------------------------------------------------------------
// per-dst-node segment softmax + weighted aggregation (+bias, +optional ELU)
// block = 256 threads = 4 waves; for H=4 each wave owns one head.
// ---------------------------------------------------------------------------
template <int H, bool ELU_OUT>
__global__ __launch_bounds__(256) void aggregate_kernel(
    const float* __restrict__ XH, const float* __restrict__ a_s,
    const float* __restrict__ a_d, const int* __restrict__ row_ptr,
    const int* __restrict__ csr_src, const float* __restrict__ bias,
    float* __restrict__ out) {
  const int d = blockIdx.x;
  const int t = threadIdx.x;
  const int lane = t & 63, w = t >> 6;
  const int e0 = row_ptr[d];
  const int deg = row_ptr[d + 1] - e0;
  const float adv = a_d[(size_t)d * H + ((H == 4) ? w : 0)];

  __shared__ float alpha_sh[256];
  __shared__ int src_sh[256];
  __shared__ float red[4];

  // ---- pass A: per-head max over incoming edges ----
  float m = -1e30f;
  if constexpr (H == 4) {
    for (int i = lane; i < deg; i += 64) {
      int s = csr_src[e0 + i];
      float e = a_s[s * 4 + w] + adv;
      e = (e > 0.f) ? e : 0.2f * e;
      m = fmaxf(m, e);
    }
#pragma unroll
    for (int off = 1; off < 64; off <<= 1) m = fmaxf(m, __shfl_xor(m, off, 64));
  } else {
    for (int i = t; i < deg; i += 256) {
      int s = csr_src[e0 + i];
      float e = a_s[s] + adv;
      e = (e > 0.f) ? e : 0.2f * e;
      m = fmaxf(m, e);
    }
#pragma unroll
    for (int off = 1; off < 64; off <<= 1) m = fmaxf(m, __shfl_xor(m, off, 64));
    if (lane == 0) red[w] = m;
    __syncthreads();
    m = fmaxf(fmaxf(red[0], red[1]), fmaxf(red[2], red[3]));
    __syncthreads();
  }

  // ---- pass B: denom ----
  float dn = 0.f;
  if constexpr (H == 4) {
    for (int i = lane; i < deg; i += 64) {
      int s = csr_src[e0 + i];
      float e = a_s[s * 4 + w] + adv;
      e = (e > 0.f) ? e : 0.2f * e;
      dn += __expf(e - m);
    }
#pragma unroll
    for (int off = 1; off < 64; off <<= 1) dn += __shfl_xor(dn, off, 64);
  } else {
    for (int i = t; i < deg; i += 256) {
      int s = csr_src[e0 + i];
      float e = a_s[s] + adv;
      e = (e > 0.f) ? e : 0.2f * e;
      dn += __expf(e - m);
    }
#pragma unroll
    for (int off = 1; off < 64; off <<= 1) dn += __shfl_xor(dn, off, 64);
    if (lane == 0) red[w] = dn;
    __syncthreads();
    dn = red[0] + red[1] + red[2] + red[3];
    __syncthreads();
  }
  const float inv = 1.f / (dn + 1e-16f);

  // ---- pass C: alpha-weighted gather of XH[src] rows ----
  float acc = 0.f;
  constexpr int CHUNK = (H == 4) ? 64 : 256;
  for (int base = 0; base < deg; base += CHUNK) {
    int cnt = min(CHUNK, deg - base);
    __syncthreads();
    if constexpr (H == 4) {
      if (lane < cnt) {
        int s = csr_src[e0 + base + lane];
        float e = a_s[s * 4 + w] + adv;
        e = (e > 0.f) ? e : 0.2f * e;
        alpha_sh[w * 64 + lane] = __expf(e - m) * inv;
        if (w == 0) src_sh[lane] = s;
      }
    } else {
      if (t < cnt) {
        int s = csr_src[e0 + base + t];
        float e = a_s[s] + adv;
        e = (e > 0.f) ? e : 0.2f * e;
        alpha_sh[t] = __expf(e - m) * inv;
        src_sh[t] = s;
      }
    }
    __syncthreads();
    for (int j = 0; j < cnt; j++) {
      int s = src_sh[j];
      float al = (H == 4) ? alpha_sh[w * 64 + j] : alpha_sh[j];
      acc = fmaf(al, XH[(size_t)s * 256 + t], acc);
    }
  }

  float v = acc + bias[t];
  if constexpr (ELU_OUT) v = (v > 0.f) ? v : (__expf(v) - 1.f);
  out[(size_t)d * 256 + t] = v;
}

// ---------------------------------------------------------------------------
extern "C" void kernel_launch(void* const* d_in, const int* in_sizes, int n_in,
                              void* d_out, int out_size, void* d_ws, size_t ws_size,
                              hipStream_t stream) {
  const float* x = (const float*)d_in[0];
  const int* ei = (const int*)d_in[1];
  const float* W0 = (const float*)d_in[2];
  const float* as0 = (const float*)d_in[3];
  const float* ad0 = (const float*)d_in[4];
  const float* b0 = (const float*)d_in[5];
  const float* W1 = (const float*)d_in[6];
  const float* as1 = (const float*)d_in[7];
  const float* ad1 = (const float*)d_in[8];
  const float* b1 = (const float*)d_in[9];
  const float* W2 = (const float*)d_in[10];
  const float* as2 = (const float*)d_in[11];
  const float* ad2 = (const float*)d_in[12];
  const float* b2 = (const float*)d_in[13];
  float* out = (float*)d_out;

  char* p = (char*)d_ws;
  float* bufA = (float*)p;
  p += (size_t)N_NODES * 256 * 4; // 51.2 MB: XH scratch
  float* a_s = (float*)p;
  p += (size_t)N_NODES * 4 * 4;
  float* a_d = (float*)p;
  p += (size_t)N_NODES * 4 * 4;
  int* row_ptr = (int*)p;
  p += 200064; // (N_NODES+1)*4 padded
  int* deg = (int*)p;
  p += (size_t)N_NODES * 4;
  int* cursor = (int*)p;
  p += (size_t)N_NODES * 4;
  int* csr_src = (int*)p;
  p += (size_t)E_TOTAL * 4;

  hipMemsetAsync(deg, 0, (size_t)N_NODES * 4, stream);
  hipMemsetAsync(cursor, 0, (size_t)N_NODES * 4, stream);
  deg_kernel<<<(E_TOTAL + 255) / 256, 256, 0, stream>>>(ei, deg);
  scan_kernel<<<1, 1024, 0, stream>>>(deg, row_ptr);
  scatter_kernel<<<(E_TOTAL + 255) / 256, 256, 0, stream>>>(ei, row_ptr, cursor, csr_src);

  dim3 ggrid((N_NODES + 63) / 64, 4);
  // layer 0: 4 heads x 64, concat, ELU
  gemm_f32<<<ggrid, 256, 0, stream>>>(x, W0, bufA, N_NODES);
  att_kernel<4><<<N_NODES, 256, 0, stream>>>(bufA, as0, ad0, a_s, a_d);
  aggregate_kernel<4, true><<<N_NODES, 256, 0, stream>>>(bufA, a_s, a_d, row_ptr, csr_src, b0, out);
  // layer 1
  gemm_f32<<<ggrid, 256, 0, stream>>>(out, W1, bufA, N_NODES);
  att_kernel<4><<<N_NODES, 256, 0, stream>>>(bufA, as1, ad1, a_s, a_d);
  aggregate_kernel<4, true><<<N_NODES, 256, 0, stream>>>(bufA, a_s, a_d, row_ptr, csr_src, b1, out);
  // layer 2: 1 head x 256, mean(=identity), no ELU
  gemm_f32<<<ggrid, 256, 0, stream>>>(out, W2, bufA, N_NODES);
  att_kernel<1><<<N_NODES, 256, 0, stream>>>(bufA, as2, ad2, a_s, a_d);
  aggregate_kernel<1, false><<<N_NODES, 256, 0, stream>>>(bufA, a_s, a_d, row_ptr, csr_src, b2, out);
}

// Round 2
// 761.813 us; speedup vs baseline: 1.1906x; 1.1906x over previous
//
#include <hip/hip_runtime.h>
#include <hip/hip_bf16.h>
#include <hip/hip_fp16.h>

#define N_NODES 50000
#define N_EDGES 800000
#define E_TOTAL (N_EDGES + N_NODES) /* 850000, self-loops appended */

// ---------------------------------------------------------------------------
// CSR build: degree count -> exclusive scan -> scatter (by dst)
// ---------------------------------------------------------------------------
__global__ __launch_bounds__(256) void deg_kernel(const int* __restrict__ ei,
                                                  int* __restrict__ deg) {
  int e = blockIdx.x * 256 + threadIdx.x;
  if (e >= E_TOTAL) return;
  int d = (e < N_EDGES) ? ei[N_EDGES + e] : (e - N_EDGES);
  atomicAdd(&deg[d], 1);
}

__global__ __launch_bounds__(1024) void scan_kernel(const int* __restrict__ deg,
                                                    int* __restrict__ row_ptr) {
  __shared__ int sh[1024];
  __shared__ int carry_sh;
  const int t = threadIdx.x;
  if (t == 0) carry_sh = 0;
  __syncthreads();
  const int ITEMS = 8;
  for (int base = 0; base < N_NODES; base += 1024 * ITEMS) {
    int i0 = base + t * ITEMS;
    int v[ITEMS];
    int s = 0;
#pragma unroll
    for (int j = 0; j < ITEMS; j++) {
      v[j] = (i0 + j < N_NODES) ? deg[i0 + j] : 0;
      s += v[j];
    }
    sh[t] = s;
    __syncthreads();
    for (int off = 1; off < 1024; off <<= 1) {
      int tv = (t >= off) ? sh[t - off] : 0;
      __syncthreads();
      sh[t] += tv;
      __syncthreads();
    }
    int excl = sh[t] - s;
    int run = carry_sh + excl;
#pragma unroll
    for (int j = 0; j < ITEMS; j++) {
      if (i0 + j < N_NODES) row_ptr[i0 + j] = run;
      run += v[j];
    }
    int total = sh[1023];
    __syncthreads();
    if (t == 0) carry_sh += total;
    __syncthreads();
  }
  if (t == 0) row_ptr[N_NODES] = carry_sh;
}

__global__ __launch_bounds__(256) void scatter_kernel(const int* __restrict__ ei,
                                                      const int* __restrict__ row_ptr,
                                                      int* __restrict__ cursor,
                                                      int* __restrict__ csr_src) {
  int e = blockIdx.x * 256 + threadIdx.x;
  if (e >= E_TOTAL) return;
  int s, d;
  if (e < N_EDGES) {
    s = ei[e];
    d = ei[N_EDGES + e];
  } else {
    s = d = e - N_EDGES;
  }
  int pos = atomicAdd(&cursor[d], 1);
  csr_src[row_ptr[d] + pos] = s;
}

// ---------------------------------------------------------------------------
// f32 GEMM -> f16 out: C16[M,256] = A[M,256] * B[256,256]
// 128x128 tile, 256 threads, 8x8 microtile (cols split tx*4 and 64+tx*4)
// ---------------------------------------------------------------------------
__global__ __launch_bounds__(256) void gemm_f16out(const float* __restrict__ A,
                                                   const float* __restrict__ B,
                                                   __half* __restrict__ C, int M) {
  __shared__ float As[16][132]; // [k][row], pad 132: A-transpose writes 2-way only
  __shared__ float Bs[16][132]; // [k][col]
  const int t = threadIdx.x;
  const int tx = t & 15;   // col group: cols {tx*4..+3} U {64+tx*4..+3}
  const int ty = t >> 4;   // row group: rows ty*8..+7
  const int row0 = blockIdx.x * 128, col0 = blockIdx.y * 128;
  float acc[8][8] = {};
  for (int k0 = 0; k0 < 256; k0 += 16) {
    // stage A (transposed) and B
#pragma unroll
    for (int f = 0; f < 2; f++) {
      int idx = f * 256 + t;
      int r = idx >> 2, kc = (idx & 3) * 4;
      float4 av = make_float4(0.f, 0.f, 0.f, 0.f);
      if (row0 + r < M) av = *(const float4*)&A[(size_t)(row0 + r) * 256 + k0 + kc];
      As[kc + 0][r] = av.x;
      As[kc + 1][r] = av.y;
      As[kc + 2][r] = av.z;
      As[kc + 3][r] = av.w;
      int kr = idx >> 5, n4 = (idx & 31) * 4;
      *(float4*)&Bs[kr][n4] = *(const float4*)&B[(size_t)(k0 + kr) * 256 + col0 + n4];
    }
    __syncthreads();
    for (int k = 0; k < 16; k++) {
      float a8[8], b8[8];
      *(float4*)&a8[0] = *(const float4*)&As[k][ty * 8];
      *(float4*)&a8[4] = *(const float4*)&As[k][ty * 8 + 4];
      *(float4*)&b8[0] = *(const float4*)&Bs[k][tx * 4];
      *(float4*)&b8[4] = *(const float4*)&Bs[k][64 + tx * 4];
#pragma unroll
      for (int i = 0; i < 8; i++)
#pragma unroll
        for (int j = 0; j < 8; j++) acc[i][j] = fmaf(a8[i], b8[j], acc[i][j]);
    }
    __syncthreads();
  }
#pragma unroll
  for (int i = 0; i < 8; i++) {
    int r = row0 + ty * 8 + i;
    if (r < M) {
      __half2 p0 = __floats2half2_rn(acc[i][0], acc[i][1]);
      __half2 p1 = __floats2half2_rn(acc[i][2], acc[i][3]);
      __half2 p2 = __floats2half2_rn(acc[i][4], acc[i][5]);
      __half2 p3 = __floats2half2_rn(acc[i][6], acc[i][7]);
      float2 w0, w1;
      ((__half2*)&w0)[0] = p0;
      ((__half2*)&w0)[1] = p1;
      ((__half2*)&w1)[0] = p2;
      ((__half2*)&w1)[1] = p3;
      *(float2*)&C[(size_t)r * 256 + col0 + tx * 4] = w0;
      *(float2*)&C[(size_t)r * 256 + col0 + 64 + tx * 4] = w1;
    }
  }
}

// ---------------------------------------------------------------------------
// attention coefficients: one wave per node, lane owns 4 channels
// ---------------------------------------------------------------------------
template <int H>
__global__ __launch_bounds__(256) void att_kernel(const __half* __restrict__ XH,
                                                  const float* __restrict__ att_s,
                                                  const float* __restrict__ att_d,
                                                  float* __restrict__ a_s,
                                                  float* __restrict__ a_d) {
  const int t = threadIdx.x;
  const int lane = t & 63, w = t >> 6;
  const int n = blockIdx.x * 4 + w;
  float2 raw = *(const float2*)(XH + (size_t)n * 256 + lane * 4);
  __half2 h01 = ((const __half2*)&raw)[0];
  __half2 h23 = ((const __half2*)&raw)[1];
  float2 f01 = __half22float2(h01), f23 = __half22float2(h23);
  float4 ws = *(const float4*)&att_s[lane * 4];
  float4 wd = *(const float4*)&att_d[lane * 4];
  float vs = f01.x * ws.x + f01.y * ws.y + f23.x * ws.z + f23.y * ws.w;
  float vd = f01.x * wd.x + f01.y * wd.y + f23.x * wd.z + f23.y * wd.w;
  if constexpr (H == 4) {
#pragma unroll
    for (int off = 1; off < 16; off <<= 1) {
      vs += __shfl_xor(vs, off, 64);
      vd += __shfl_xor(vd, off, 64);
    }
    if ((lane & 15) == 0) {
      a_s[(size_t)n * 4 + (lane >> 4)] = vs;
      a_d[(size_t)n * 4 + (lane >> 4)] = vd;
    }
  } else {
#pragma unroll
    for (int off = 1; off < 64; off <<= 1) {
      vs += __shfl_xor(vs, off, 64);
      vd += __shfl_xor(vd, off, 64);
    }
    if (lane == 0) {
      a_s[n] = vs;
      a_d[n] = vd;
    }
  }
}

// ---------------------------------------------------------------------------
// segment softmax + weighted gather: ONE WAVE PER NODE, no LDS, no barriers.
// lane owns channels lane*4..+3 (head = lane>>4 for H=4).
// ---------------------------------------------------------------------------
template <int H, bool ELU_OUT>
__global__ __launch_bounds__(256) void aggregate_kernel(
    const __half* __restrict__ XH16, const float* __restrict__ a_s,
    const float* __restrict__ a_d, const int* __restrict__ row_ptr,
    const int* __restrict__ csr_src, const float* __restrict__ bias,
    float* __restrict__ out) {
  const int t = threadIdx.x;
  const int lane = t & 63, w = t >> 6;
  const int d = blockIdx.x * 4 + w;
  const int e0 = row_ptr[d];
  const int deg = row_ptr[d + 1] - e0;
  const int h4 = (H == 4) ? (lane >> 4) : 0;
  const float adv = (H == 4) ? a_d[(size_t)d * 4 + h4] : a_d[d];

  // pass A: per-head max over incoming edges
  float m = -1e30f;
  if constexpr (H == 4) {
    const int li = lane & 15;
    for (int i = li; i < deg; i += 16) {
      int s = csr_src[e0 + i];
      float e = a_s[(size_t)s * 4 + h4] + adv;
      e = e > 0.f ? e : 0.2f * e;
      m = fmaxf(m, e);
    }
#pragma unroll
    for (int off = 1; off < 16; off <<= 1) m = fmaxf(m, __shfl_xor(m, off, 64));
  } else {
    for (int i = lane; i < deg; i += 64) {
      int s = csr_src[e0 + i];
      float e = a_s[s] + adv;
      e = e > 0.f ? e : 0.2f * e;
      m = fmaxf(m, e);
    }
#pragma unroll
    for (int off = 1; off < 64; off <<= 1) m = fmaxf(m, __shfl_xor(m, off, 64));
  }

  // pass B: denom
  float dn = 0.f;
  if constexpr (H == 4) {
    const int li = lane & 15;
    for (int i = li; i < deg; i += 16) {
      int s = csr_src[e0 + i];
      float e = a_s[(size_t)s * 4 + h4] + adv;
      e = e > 0.f ? e : 0.2f * e;
      dn += __expf(e - m);
    }
#pragma unroll
    for (int off = 1; off < 16; off <<= 1) dn += __shfl_xor(dn, off, 64);
  } else {
    for (int i = lane; i < deg; i += 64) {
      int s = csr_src[e0 + i];
      float e = a_s[s] + adv;
      e = e > 0.f ? e : 0.2f * e;
      dn += __expf(e - m);
    }
#pragma unroll
    for (int off = 1; off < 64; off <<= 1) dn += __shfl_xor(dn, off, 64);
  }
  const float inv = 1.f / (dn + 1e-16f);

  // gather: per edge, whole 512B f16 row read by the wave (8B/lane)
  float acc0 = 0.f, acc1 = 0.f, acc2 = 0.f, acc3 = 0.f;
  for (int j = 0; j < deg; j++) {
    int s = csr_src[e0 + j];
    s = __builtin_amdgcn_readfirstlane(s); // wave-uniform: scalarize addressing
    float e = ((H == 4) ? a_s[(size_t)s * 4 + h4] : a_s[s]) + adv;
    e = e > 0.f ? e : 0.2f * e;
    float al = __expf(e - m) * inv;
    float2 raw = *(const float2*)(XH16 + (size_t)s * 256 + lane * 4);
    __half2 h01 = ((const __half2*)&raw)[0];
    __half2 h23 = ((const __half2*)&raw)[1];
    float2 f01 = __half22float2(h01);
    float2 f23 = __half22float2(h23);
    acc0 = fmaf(al, f01.x, acc0);
    acc1 = fmaf(al, f01.y, acc1);
    acc2 = fmaf(al, f23.x, acc2);
    acc3 = fmaf(al, f23.y, acc3);
  }

  float4 bv = *(const float4*)&bias[lane * 4];
  float v0 = acc0 + bv.x, v1 = acc1 + bv.y, v2 = acc2 + bv.z, v3 = acc3 + bv.w;
  if constexpr (ELU_OUT) {
    v0 = v0 > 0.f ? v0 : (__expf(v0) - 1.f);
    v1 = v1 > 0.f ? v1 : (__expf(v1) - 1.f);
    v2 = v2 > 0.f ? v2 : (__expf(v2) - 1.f);
    v3 = v3 > 0.f ? v3 : (__expf(v3) - 1.f);
  }
  *(float4*)&out[(size_t)d * 256 + lane * 4] = make_float4(v0, v1, v2, v3);
}

// ---------------------------------------------------------------------------
extern "C" void kernel_launch(void* const* d_in, const int* in_sizes, int n_in,
                              void* d_out, int out_size, void* d_ws, size_t ws_size,
                              hipStream_t stream) {
  const float* x = (const float*)d_in[0];
  const int* ei = (const int*)d_in[1];
  const float* W0 = (const float*)d_in[2];
  const float* as0 = (const float*)d_in[3];
  const float* ad0 = (const float*)d_in[4];
  const float* b0 = (const float*)d_in[5];
  const float* W1 = (const float*)d_in[6];
  const float* as1 = (const float*)d_in[7];
  const float* ad1 = (const float*)d_in[8];
  const float* b1 = (const float*)d_in[9];
  const float* W2 = (const float*)d_in[10];
  const float* as2 = (const float*)d_in[11];
  const float* ad2 = (const float*)d_in[12];
  const float* b2 = (const float*)d_in[13];
  float* out = (float*)d_out;

  char* p = (char*)d_ws;
  __half* XH16 = (__half*)p;
  p += (size_t)N_NODES * 256 * 2; // 25.6 MB f16 feature table
  float* a_s = (float*)p;
  p += (size_t)N_NODES * 4 * 4;
  float* a_d = (float*)p;
  p += (size_t)N_NODES * 4 * 4;
  int* row_ptr = (int*)p;
  p += 200064; // (N_NODES+1)*4 padded
  int* deg = (int*)p;
  p += (size_t)N_NODES * 4;
  int* cursor = (int*)p;
  p += (size_t)N_NODES * 4;
  int* csr_src = (int*)p;
  p += (size_t)E_TOTAL * 4;

  hipMemsetAsync(deg, 0, (size_t)N_NODES * 4, stream);
  hipMemsetAsync(cursor, 0, (size_t)N_NODES * 4, stream);
  deg_kernel<<<(E_TOTAL + 255) / 256, 256, 0, stream>>>(ei, deg);
  scan_kernel<<<1, 1024, 0, stream>>>(deg, row_ptr);
  scatter_kernel<<<(E_TOTAL + 255) / 256, 256, 0, stream>>>(ei, row_ptr, cursor, csr_src);

  dim3 ggrid((N_NODES + 127) / 128, 2);
  const int ngrid = N_NODES / 4; // 12500, exact

  // layer 0: 4 heads x 64, concat, ELU
  gemm_f16out<<<ggrid, 256, 0, stream>>>(x, W0, XH16, N_NODES);
  att_kernel<4><<<ngrid, 256, 0, stream>>>(XH16, as0, ad0, a_s, a_d);
  aggregate_kernel<4, true><<<ngrid, 256, 0, stream>>>(XH16, a_s, a_d, row_ptr, csr_src, b0, out);
  // layer 1
  gemm_f16out<<<ggrid, 256, 0, stream>>>(out, W1, XH16, N_NODES);
  att_kernel<4><<<ngrid, 256, 0, stream>>>(XH16, as1, ad1, a_s, a_d);
  aggregate_kernel<4, true><<<ngrid, 256, 0, stream>>>(XH16, a_s, a_d, row_ptr, csr_src, b1, out);
  // layer 2: 1 head x 256, mean over 1 head = identity, no ELU
  gemm_f16out<<<ggrid, 256, 0, stream>>>(out, W2, XH16, N_NODES);
  att_kernel<1><<<ngrid, 256, 0, stream>>>(XH16, as2, ad2, a_s, a_d);
  aggregate_kernel<1, false><<<ngrid, 256, 0, stream>>>(XH16, a_s, a_d, row_ptr, csr_src, b2, out);
}

// Round 4
// 470.760 us; speedup vs baseline: 1.9268x; 1.6183x over previous
//
#include <hip/hip_runtime.h>
#include <hip/hip_bf16.h>
#include <hip/hip_fp16.h>

#define N_NODES 50000
#define N_EDGES 800000
#define E_TOTAL (N_EDGES + N_NODES) /* 850000, self-loops appended */

typedef _Float16 f16x8 __attribute__((ext_vector_type(8)));
typedef _Float16 f16x4 __attribute__((ext_vector_type(4)));
typedef float f32x4 __attribute__((ext_vector_type(4)));

// ---------------------------------------------------------------------------
// CSR build: degree count -> exclusive scan -> scatter (by dst)
// ---------------------------------------------------------------------------
__global__ __launch_bounds__(256) void deg_kernel(const int* __restrict__ ei,
                                                  int* __restrict__ deg) {
  int e = blockIdx.x * 256 + threadIdx.x;
  if (e >= E_TOTAL) return;
  int d = (e < N_EDGES) ? ei[N_EDGES + e] : (e - N_EDGES);
  atomicAdd(&deg[d], 1);
}

__global__ __launch_bounds__(1024) void scan_kernel(const int* __restrict__ deg,
                                                    int* __restrict__ row_ptr) {
  __shared__ int sh[1024];
  __shared__ int carry_sh;
  const int t = threadIdx.x;
  if (t == 0) carry_sh = 0;
  __syncthreads();
  const int ITEMS = 8;
  for (int base = 0; base < N_NODES; base += 1024 * ITEMS) {
    int i0 = base + t * ITEMS;
    int v[ITEMS];
    int s = 0;
#pragma unroll
    for (int j = 0; j < ITEMS; j++) {
      v[j] = (i0 + j < N_NODES) ? deg[i0 + j] : 0;
      s += v[j];
    }
    sh[t] = s;
    __syncthreads();
    for (int off = 1; off < 1024; off <<= 1) {
      int tv = (t >= off) ? sh[t - off] : 0;
      __syncthreads();
      sh[t] += tv;
      __syncthreads();
    }
    int excl = sh[t] - s;
    int run = carry_sh + excl;
#pragma unroll
    for (int j = 0; j < ITEMS; j++) {
      if (i0 + j < N_NODES) row_ptr[i0 + j] = run;
      run += v[j];
    }
    int total = sh[1023];
    __syncthreads();
    if (t == 0) carry_sh += total;
    __syncthreads();
  }
  if (t == 0) row_ptr[N_NODES] = carry_sh;
}

__global__ __launch_bounds__(256) void scatter_kernel(const int* __restrict__ ei,
                                                      const int* __restrict__ row_ptr,
                                                      int* __restrict__ cursor,
                                                      int* __restrict__ csr_src) {
  int e = blockIdx.x * 256 + threadIdx.x;
  if (e >= E_TOTAL) return;
  int s, d;
  if (e < N_EDGES) {
    s = ei[e];
    d = ei[N_EDGES + e];
  } else {
    s = d = e - N_EDGES;
  }
  int pos = atomicAdd(&cursor[d], 1);
  csr_src[row_ptr[d] + pos] = s;
}

// ---------------------------------------------------------------------------
// W transpose: WT[n][k] = (f16) W[k][n], 256x256
// ---------------------------------------------------------------------------
__global__ __launch_bounds__(256) void transpose_w(const float* __restrict__ W,
                                                   _Float16* __restrict__ WT) {
  __shared__ float tile[32][33];
  const int bx = blockIdx.x * 32, by = blockIdx.y * 32;
  const int tx = threadIdx.x & 31, ty = threadIdx.x >> 5;
#pragma unroll
  for (int i = 0; i < 32; i += 8) tile[ty + i][tx] = W[(size_t)(by + ty + i) * 256 + bx + tx];
  __syncthreads();
#pragma unroll
  for (int i = 0; i < 32; i += 8)
    WT[(size_t)(bx + ty + i) * 256 + by + tx] = (_Float16)tile[tx][ty + i];
}

// ---------------------------------------------------------------------------
// MFMA f16 GEMM: C16[M,256] = A[M,256] * W, with WT[n][k] pre-transposed f16.
// 128x128 tile, 4 waves in 2x2, each wave 64x64 (4x4 frags of 16x16x32).
// LDS [128][40] f16 padded -> 2-way bank conflicts only (free).
// ---------------------------------------------------------------------------
template <bool A_IS_F16>
__global__ __launch_bounds__(256) void gemm_mfma(const void* __restrict__ Ap,
                                                 const _Float16* __restrict__ WT,
                                                 _Float16* __restrict__ C, int M) {
  __shared__ _Float16 As[128][40];
  __shared__ _Float16 Bs[128][40];
  const int t = threadIdx.x;
  const int lane = t & 63, w = t >> 6;
  const int wr = w & 1, wc = w >> 1;
  const int row0 = blockIdx.x * 128, col0 = blockIdx.y * 128;
  const int fr = lane & 15, fg = lane >> 4; // frag row/col and k-group

  f32x4 acc[4][4] = {};

  for (int k0 = 0; k0 < 256; k0 += 32) {
    // stage A (f32->f16 or f16 copy) and B (f16 copy from WT):
    // tile is 128 rows x 32 k = 512 f16x8 chunks, 2 per thread.
#pragma unroll
    for (int f = 0; f < 2; f++) {
      const int idx = f * 256 + t;
      const int sr = idx >> 2, sc = idx & 3;
      f16x8 va;
      if constexpr (A_IS_F16) {
        const _Float16* A = (const _Float16*)Ap;
        va = (row0 + sr < M) ? *(const f16x8*)(A + (size_t)(row0 + sr) * 256 + k0 + sc * 8)
                             : f16x8{};
      } else {
        const float* A = (const float*)Ap;
        va = f16x8{};
        if (row0 + sr < M) {
          float4 u0 = *(const float4*)(A + (size_t)(row0 + sr) * 256 + k0 + sc * 8);
          float4 u1 = *(const float4*)(A + (size_t)(row0 + sr) * 256 + k0 + sc * 8 + 4);
          va[0] = (_Float16)u0.x; va[1] = (_Float16)u0.y;
          va[2] = (_Float16)u0.z; va[3] = (_Float16)u0.w;
          va[4] = (_Float16)u1.x; va[5] = (_Float16)u1.y;
          va[6] = (_Float16)u1.z; va[7] = (_Float16)u1.w;
        }
      }
      f16x8 vb = *(const f16x8*)(WT + (size_t)(col0 + sr) * 256 + k0 + sc * 8);
      *(f16x8*)&As[sr][sc * 8] = va;
      *(f16x8*)&Bs[sr][sc * 8] = vb;
    }
    __syncthreads();

    f16x8 af[4], bf[4];
#pragma unroll
    for (int mi = 0; mi < 4; mi++) af[mi] = *(const f16x8*)&As[wr * 64 + mi * 16 + fr][fg * 8];
#pragma unroll
    for (int ni = 0; ni < 4; ni++) bf[ni] = *(const f16x8*)&Bs[wc * 64 + ni * 16 + fr][fg * 8];
#pragma unroll
    for (int mi = 0; mi < 4; mi++)
#pragma unroll
      for (int ni = 0; ni < 4; ni++)
        acc[mi][ni] = __builtin_amdgcn_mfma_f32_16x16x32_f16(af[mi], bf[ni], acc[mi][ni], 0, 0, 0);
    __syncthreads();
  }

  // epilogue: D col = lane&15, row = (lane>>4)*4 + reg  [m89 layout]
#pragma unroll
  for (int mi = 0; mi < 4; mi++) {
#pragma unroll
    for (int reg = 0; reg < 4; reg++) {
      int r = row0 + wr * 64 + mi * 16 + fg * 4 + reg;
      if (r < M) {
#pragma unroll
        for (int ni = 0; ni < 4; ni++) {
          int cc = col0 + wc * 64 + ni * 16 + fr;
          C[(size_t)r * 256 + cc] = (_Float16)acc[mi][ni][reg];
        }
      }
    }
  }
}

// ---------------------------------------------------------------------------
// attention coefficients: one wave per node, lane owns 4 channels
// ---------------------------------------------------------------------------
template <int H>
__global__ __launch_bounds__(256) void att_kernel(const _Float16* __restrict__ XH,
                                                  const float* __restrict__ att_s,
                                                  const float* __restrict__ att_d,
                                                  float* __restrict__ a_s,
                                                  float* __restrict__ a_d) {
  const int t = threadIdx.x;
  const int lane = t & 63, w = t >> 6;
  const int n = blockIdx.x * 4 + w;
  f16x4 raw = *(const f16x4*)(XH + (size_t)n * 256 + lane * 4);
  float4 ws = *(const float4*)&att_s[lane * 4];
  float4 wd = *(const float4*)&att_d[lane * 4];
  float f0 = (float)raw[0], f1 = (float)raw[1], f2 = (float)raw[2], f3 = (float)raw[3];
  float vs = f0 * ws.x + f1 * ws.y + f2 * ws.z + f3 * ws.w;
  float vd = f0 * wd.x + f1 * wd.y + f2 * wd.z + f3 * wd.w;
  if constexpr (H == 4) {
#pragma unroll
    for (int off = 1; off < 16; off <<= 1) {
      vs += __shfl_xor(vs, off, 64);
      vd += __shfl_xor(vd, off, 64);
    }
    if ((lane & 15) == 0) {
      a_s[(size_t)n * 4 + (lane >> 4)] = vs;
      a_d[(size_t)n * 4 + (lane >> 4)] = vd;
    }
  } else {
#pragma unroll
    for (int off = 1; off < 64; off <<= 1) {
      vs += __shfl_xor(vs, off, 64);
      vd += __shfl_xor(vd, off, 64);
    }
    if (lane == 0) {
      a_s[n] = vs;
      a_d[n] = vd;
    }
  }
}

// ---------------------------------------------------------------------------
// segment softmax + weighted gather: one wave per node, chunk-16 edges,
// alphas computed in parallel (lane&15 = edge, lane>>4 = head), shfl
// broadcast, 16 row-loads in flight in the unrolled inner loop.
// ---------------------------------------------------------------------------
template <int H, bool ELU_OUT, bool OUT_F16>
__global__ __launch_bounds__(256) void aggregate_kernel(
    const _Float16* __restrict__ XH16, const float* __restrict__ a_s,
    const float* __restrict__ a_d, const int* __restrict__ row_ptr,
    const int* __restrict__ csr_src, const float* __restrict__ bias,
    void* __restrict__ outp) {
  const int t = threadIdx.x;
  const int lane = t & 63, w = t >> 6;
  const int d = blockIdx.x * 4 + w;
  const int e0 = row_ptr[d];
  const int deg = row_ptr[d + 1] - e0;
  const int h4 = (H == 4) ? (lane >> 4) : 0;
  const float adv = (H == 4) ? a_d[(size_t)d * 4 + h4] : a_d[d];

  // pass A: per-head max
  float m = -1e30f;
  if constexpr (H == 4) {
    for (int i = lane & 15; i < deg; i += 16) {
      int s = csr_src[e0 + i];
      float e = a_s[(size_t)s * 4 + h4] + adv;
      e = e > 0.f ? e : 0.2f * e;
      m = fmaxf(m, e);
    }
#pragma unroll
    for (int off = 1; off < 16; off <<= 1) m = fmaxf(m, __shfl_xor(m, off, 64));
  } else {
    for (int i = lane; i < deg; i += 64) {
      int s = csr_src[e0 + i];
      float e = a_s[s] + adv;
      e = e > 0.f ? e : 0.2f * e;
      m = fmaxf(m, e);
    }
#pragma unroll
    for (int off = 1; off < 64; off <<= 1) m = fmaxf(m, __shfl_xor(m, off, 64));
  }

  // pass B: denom
  float dn = 0.f;
  if constexpr (H == 4) {
    for (int i = lane & 15; i < deg; i += 16) {
      int s = csr_src[e0 + i];
      float e = a_s[(size_t)s * 4 + h4] + adv;
      e = e > 0.f ? e : 0.2f * e;
      dn += __expf(e - m);
    }
#pragma unroll
    for (int off = 1; off < 16; off <<= 1) dn += __shfl_xor(dn, off, 64);
  } else {
    for (int i = lane; i < deg; i += 64) {
      int s = csr_src[e0 + i];
      float e = a_s[s] + adv;
      e = e > 0.f ? e : 0.2f * e;
      dn += __expf(e - m);
    }
#pragma unroll
    for (int off = 1; off < 64; off <<= 1) dn += __shfl_xor(dn, off, 64);
  }
  const float inv = 1.f / (dn + 1e-16f);

  // gather in chunks of 16 edges
  float acc0 = 0.f, acc1 = 0.f, acc2 = 0.f, acc3 = 0.f;
  const int li = lane & 15;
  for (int base = 0; base < deg; base += 16) {
    const int cnt = min(16, deg - base);
    int s = 0;
    float al = 0.f;
    if (li < cnt) {
      s = csr_src[e0 + base + li];
      float e = ((H == 4) ? a_s[(size_t)s * 4 + h4] : a_s[s]) + adv;
      e = e > 0.f ? e : 0.2f * e;
      al = __expf(e - m) * inv;
    }
#define GAT_BODY(j)                                                          \
  {                                                                          \
    int sj = __builtin_amdgcn_readfirstlane(__shfl(s, (j), 64));             \
    float alj = __shfl(al, (lane & 48) + (j), 64);                           \
    f16x4 raw = *(const f16x4*)(XH16 + (size_t)sj * 256 + lane * 4);         \
    acc0 = fmaf(alj, (float)raw[0], acc0);                                   \
    acc1 = fmaf(alj, (float)raw[1], acc1);                                   \
    acc2 = fmaf(alj, (float)raw[2], acc2);                                   \
    acc3 = fmaf(alj, (float)raw[3], acc3);                                   \
  }
    if (cnt == 16) {
#pragma unroll
      for (int j = 0; j < 16; j++) GAT_BODY(j)
    } else {
      for (int j = 0; j < cnt; j++) GAT_BODY(j)
    }
#undef GAT_BODY
  }

  float4 bv = *(const float4*)&bias[lane * 4];
  float v0 = acc0 + bv.x, v1 = acc1 + bv.y, v2 = acc2 + bv.z, v3 = acc3 + bv.w;
  if constexpr (ELU_OUT) {
    v0 = v0 > 0.f ? v0 : (__expf(v0) - 1.f);
    v1 = v1 > 0.f ? v1 : (__expf(v1) - 1.f);
    v2 = v2 > 0.f ? v2 : (__expf(v2) - 1.f);
    v3 = v3 > 0.f ? v3 : (__expf(v3) - 1.f);
  }
  if constexpr (OUT_F16) {
    _Float16* out = (_Float16*)outp;
    f16x4 ov;
    ov[0] = (_Float16)v0; ov[1] = (_Float16)v1;
    ov[2] = (_Float16)v2; ov[3] = (_Float16)v3;
    *(f16x4*)(out + (size_t)d * 256 + lane * 4) = ov;
  } else {
    float* out = (float*)outp;
    *(float4*)(out + (size_t)d * 256 + lane * 4) = make_float4(v0, v1, v2, v3);
  }
}

// ---------------------------------------------------------------------------
extern "C" void kernel_launch(void* const* d_in, const int* in_sizes, int n_in,
                              void* d_out, int out_size, void* d_ws, size_t ws_size,
                              hipStream_t stream) {
  const float* x = (const float*)d_in[0];
  const int* ei = (const int*)d_in[1];
  const float* W0 = (const float*)d_in[2];
  const float* as0 = (const float*)d_in[3];
  const float* ad0 = (const float*)d_in[4];
  const float* b0 = (const float*)d_in[5];
  const float* W1 = (const float*)d_in[6];
  const float* as1 = (const float*)d_in[7];
  const float* ad1 = (const float*)d_in[8];
  const float* b1 = (const float*)d_in[9];
  const float* W2 = (const float*)d_in[10];
  const float* as2 = (const float*)d_in[11];
  const float* ad2 = (const float*)d_in[12];
  const float* b2 = (const float*)d_in[13];
  float* out = (float*)d_out;

  char* p = (char*)d_ws;
  _Float16* XH16 = (_Float16*)p;
  p += (size_t)N_NODES * 256 * 2; // 25.6 MB: GEMM out / gather table
  _Float16* H16 = (_Float16*)p;
  p += (size_t)N_NODES * 256 * 2; // 25.6 MB: aggregate out -> next GEMM in
  _Float16* WT = (_Float16*)p;
  p += 256 * 256 * 2; // 128 KB transposed weights
  float* a_s = (float*)p;
  p += (size_t)N_NODES * 4 * 4;
  float* a_d = (float*)p;
  p += (size_t)N_NODES * 4 * 4;
  int* row_ptr = (int*)p;
  p += 200064;
  int* deg = (int*)p;
  p += (size_t)N_NODES * 4;
  int* cursor = (int*)p;
  p += (size_t)N_NODES * 4;
  int* csr_src = (int*)p;
  p += (size_t)E_TOTAL * 4;

  hipMemsetAsync(deg, 0, (size_t)N_NODES * 4, stream);
  hipMemsetAsync(cursor, 0, (size_t)N_NODES * 4, stream);
  deg_kernel<<<(E_TOTAL + 255) / 256, 256, 0, stream>>>(ei, deg);
  scan_kernel<<<1, 1024, 0, stream>>>(deg, row_ptr);
  scatter_kernel<<<(E_TOTAL + 255) / 256, 256, 0, stream>>>(ei, row_ptr, cursor, csr_src);

  dim3 tgrid(8, 8);
  dim3 ggrid((N_NODES + 127) / 128, 2);
  const int ngrid = N_NODES / 4; // 12500, exact

  // layer 0: 4 heads x 64, concat, ELU
  transpose_w<<<tgrid, 256, 0, stream>>>(W0, WT);
  gemm_mfma<false><<<ggrid, 256, 0, stream>>>(x, WT, XH16, N_NODES);
  att_kernel<4><<<ngrid, 256, 0, stream>>>(XH16, as0, ad0, a_s, a_d);
  aggregate_kernel<4, true, true><<<ngrid, 256, 0, stream>>>(XH16, a_s, a_d, row_ptr, csr_src, b0, H16);
  // layer 1
  transpose_w<<<tgrid, 256, 0, stream>>>(W1, WT);
  gemm_mfma<true><<<ggrid, 256, 0, stream>>>(H16, WT, XH16, N_NODES);
  att_kernel<4><<<ngrid, 256, 0, stream>>>(XH16, as1, ad1, a_s, a_d);
  aggregate_kernel<4, true, true><<<ngrid, 256, 0, stream>>>(XH16, a_s, a_d, row_ptr, csr_src, b1, H16);
  // layer 2: 1 head x 256, mean over 1 head = identity, no ELU, f32 out
  transpose_w<<<tgrid, 256, 0, stream>>>(W2, WT);
  gemm_mfma<true><<<ggrid, 256, 0, stream>>>(H16, WT, XH16, N_NODES);
  att_kernel<1><<<ngrid, 256, 0, stream>>>(XH16, as2, ad2, a_s, a_d);
  aggregate_kernel<1, false, false><<<ngrid, 256, 0, stream>>>(XH16, a_s, a_d, row_ptr, csr_src, b2, out);
}